// Round 1
// baseline (72.502 us; speedup 1.0000x reference)
//
#include <hip/hip_runtime.h>
#include <math.h>

// RoI "mod-7" max pooling (JAX reference-exact).
// x: (2, 512, 50, 50) fp32; rois: (R,5) fp32 [b, y1, x1, y2, x2]*16; out: (R, 512, 7, 7).
//
// R4 redesign: bin-aligned lane mapping kills the shuffle reduce.
//   lane = g*8 + j   (g = channel 0..7, j = bin column 0..6; j==7 idle)
//   lane j loads columns {j, j+7, j+14, j+21} -> every value already belongs
//   to bin j, so the column reduce is a per-lane fmax chain (0 DS ops) and
//   the store writes 56 active lanes (8 ch x 7 bins) per instruction.
//   nk = ceil(ftw/7) is wave-uniform -> k-groups past the window are skipped
//   entirely (avg ftw ~13 -> 2 loads/row/8ch instead of 4).
// Column OOB kept as R3: clamped (always in-bounds) address + one v_cndmask
// to -inf per load; row validity is scalar control flow (full super-rows +
// <=6 tail rows behind s_cbranch).
// 8 channels/wave -> grid (16, R) x 256 thr = 8192 waves = 32/CU, ONE round.

#define CH 512
#define IH 50
#define IW 50
#define NEG_INF (-__builtin_inff())

template <int NK>
__device__ __forceinline__ void walk(const float* __restrict__ xp,
                                     uint32_t (&voff)[4],
                                     const bool (&colok)[4],
                                     int full, int remh, float (&acc)[7]) {
  // Full super-rows: 7*NK independent unmasked loads per iteration.
  for (int s = 0; s < full; ++s) {
#pragma unroll
    for (int i = 0; i < 7; ++i) {
#pragma unroll
      for (int k = 0; k < NK; ++k) {
        float v = xp[voff[k] + (uint32_t)(i * IW)];   // imm offset: i*200 B
        acc[i] = fmaxf(acc[i], colok[k] ? v : NEG_INF);
      }
    }
#pragma unroll
    for (int k = 0; k < NK; ++k) voff[k] += 7u * IW;
  }
  // Tail rows (0..6, wave-uniform count -> scalar skip branches).
#pragma unroll
  for (int i = 0; i < 7; ++i) {
    if (i < remh) {
#pragma unroll
      for (int k = 0; k < NK; ++k) {
        float v = xp[voff[k] + (uint32_t)(i * IW)];
        acc[i] = fmaxf(acc[i], colok[k] ? v : NEG_INF);
      }
    }
  }
}

__global__ __launch_bounds__(256) void roipool_kernel(
    const float* __restrict__ x, const float* __restrict__ rois,
    float* __restrict__ out) {
  const int r    = blockIdx.y;
  const int wave = threadIdx.x >> 6;   // 0..3
  const int lane = threadIdx.x & 63;
  const int g    = lane >> 3;          // channel within wave (0..7)
  const int j    = lane & 7;           // output bin column (j==7 -> idle lane)

  // roi decode, forced wave-uniform (SGPRs -> scalar branches, scalar strides).
  const float* rr = rois + r * 5;
  const int b  = __builtin_amdgcn_readfirstlane((int)rr[0]);
  const int y1 = __builtin_amdgcn_readfirstlane((int)rintf(rr[1] * 0.0625f));
  const int x1 = __builtin_amdgcn_readfirstlane((int)rintf(rr[2] * 0.0625f));
  const int y2 = __builtin_amdgcn_readfirstlane(min((int)rintf(rr[3] * 0.0625f), IH - 1));
  const int x2 = __builtin_amdgcn_readfirstlane(min((int)rintf(rr[4] * 0.0625f), IW - 1));
  const int fth  = y2 - y1 + 1;
  const int ftw  = x2 - x1 + 1;
  const int remh = fth % 7;
  const int remw = ftw % 7;
  const int full = fth / 7;

  // 8 channels per wave; 32 per block.
  const int c = (blockIdx.x * 4 + wave) * 8 + g;
  const uint32_t rowbase =
      ((uint32_t)(b * CH + c) * IH + (uint32_t)y1) * IW + (uint32_t)x1;

  // Per-k column: clamped (always in-bounds) address + validity mask.
  bool colok[4];
  uint32_t voff[4];
#pragma unroll
  for (int k = 0; k < 4; ++k) {
    const int col = j + 7 * k;
    colok[k] = (j < 7) & (col < ftw);
    voff[k]  = rowbase + (uint32_t)min(col, ftw - 1);
  }

  float acc[7];
#pragma unroll
  for (int i = 0; i < 7; ++i) acc[i] = NEG_INF;

  // nk = ceil(ftw/7) (1..4), wave-uniform -> scalar dispatch; k-groups past
  // the window cost nothing.
  const int nk = (ftw + 6) / 7;
  switch (nk) {
    case 1:  walk<1>(x, voff, colok, full, remh, acc); break;
    case 2:  walk<2>(x, voff, colok, full, remh, acc); break;
    case 3:  walk<3>(x, voff, colok, full, remh, acc); break;
    default: walk<4>(x, voff, colok, full, remh, acc); break;
  }

  // Pad-clamp (bins beyond remh/remw -> max(val, 0)) + direct store:
  // lane (g, j) owns out[r, c, :, j] -- no shuffles needed.
  if (j < 7) {
    const bool padc = (remw != 0) & (j >= remw);
    float* o = out + (size_t)(r * CH + c) * 49 + j;
#pragma unroll
    for (int i = 0; i < 7; ++i) {
      float v = acc[i];
      const bool padr = (remh != 0) & (i >= remh);
      if (padr | padc) v = fmaxf(v, 0.0f);
      o[i * 7] = v;
    }
  }
}

extern "C" void kernel_launch(void* const* d_in, const int* in_sizes, int n_in,
                              void* d_out, int out_size, void* d_ws, size_t ws_size,
                              hipStream_t stream) {
  const float* x    = (const float*)d_in[0];
  const float* rois = (const float*)d_in[1];
  float* out        = (float*)d_out;
  const int R = in_sizes[1] / 5;  // 128

  dim3 grid(16, R);   // 16 channel-groups (32 ch/block) x R rois = 2048 blocks
  dim3 block(256);    // 4 waves; each wave = 8 channels (bin-aligned lanes)
  roipool_kernel<<<grid, block, 0, stream>>>(x, rois, out);
}